// Round 16
// baseline (105.095 us; speedup 1.0000x reference)
//
#include <hip/hip_runtime.h>
#include <hip/hip_bf16.h>

#define BATCH 16
#define INP   128
#define OUP   128
#define HH    56
#define WW    56
#define HWSZ  3136
#define HID   768
#define EPSV  1e-5f

#define CPST  265             // k23 stg per-cp stride (dw): 256 DMA'd + 9 pad; odd -> DW banks clean
#define H2STR 72              // h2s ushort stride (36 dw)
#define XSTR  130             // k1 xs ushort stride (65 dw, odd)
#define H1ROW 64              // h1 padded row (dw): cols -4..59, px c at dword 4+c
#define H1RPC 58              // rows per channel-pair: guard + 56 + guard

typedef __attribute__((ext_vector_type(8))) short bf16x8;
typedef __attribute__((ext_vector_type(4))) float f32x4;
typedef __attribute__((ext_vector_type(2))) float f32x2;
typedef __attribute__((address_space(1))) const unsigned GU;
typedef __attribute__((address_space(3))) unsigned LU;

__device__ __forceinline__ unsigned short f2b(float f) {
    unsigned u = __float_as_uint(f);
    return (unsigned short)((u + 0x7FFFu + ((u >> 16) & 1u)) >> 16);   // RNE
}
__device__ __forceinline__ float blo(unsigned u){ return __uint_as_float(u << 16); }
__device__ __forceinline__ float bhi(unsigned u){ return __uint_as_float(u & 0xFFFF0000u); }
__device__ __forceinline__ unsigned pkbf(float lo, float hi) {
    unsigned r;
    asm("v_cvt_pk_bf16_f32 %0, %1, %2" : "=v"(r) : "v"(lo), "v"(hi));
    return r;
}
__device__ __forceinline__ void pkfma(f32x2& a, f32x2 b, f32x2 c) {   // a = b*c + a
    asm("v_pk_fma_f32 %0, %1, %2, %0" : "+v"(a) : "v"(b), "v"(c));
}

// ---------------- prep: fold BN into bf16 weights + mask dilate + h1 guard zeroing ----------------
__global__ void prep(const float* __restrict__ w1, const float* __restrict__ g1,
                     const float* __restrict__ b1, const float* __restrict__ m1, const float* __restrict__ v1,
                     const float* __restrict__ wdw, const float* __restrict__ g2,
                     const float* __restrict__ b2, const float* __restrict__ m2, const float* __restrict__ v2,
                     const float* __restrict__ w2, const float* __restrict__ g3,
                     const float* __restrict__ b3, const float* __restrict__ m3, const float* __restrict__ v3,
                     const int* __restrict__ mask,
                     unsigned short* __restrict__ w1f, unsigned short* __restrict__ w2f,
                     float* __restrict__ be1o, float* __restrict__ wdsf,
                     float* __restrict__ be2o, float* __restrict__ be3o,
                     float* __restrict__ mdf, float* __restrict__ mff,
                     unsigned* __restrict__ h1p)
{
    int gid = blockIdx.x * blockDim.x + threadIdx.x;
    int stp = gridDim.x * blockDim.x;
    // w1 fragment-linear: [ht 48][ks 4][g 4][r16 16][e 8]
    for (int i = gid; i < HID * INP; i += stp) {
        int r = i >> 7, k = i & 127;
        float s = g1[r] * rsqrtf(v1[r] + EPSV);
        int ht = r >> 4, r16 = r & 15, ks = k >> 5, g = (k >> 3) & 3, e = k & 7;
        w1f[((((ht * 4 + ks) * 4 + g) * 16 + r16) << 3) + e] = f2b(w1[i] * s);
    }
    // w2 fragment-linear: [ot 8][ch 12][ks 2][lane 64][e 8]
    for (int i = gid; i < OUP * HID; i += stp) {
        int r = i / HID, k = i - r * HID;
        float s = g3[r] * rsqrtf(v3[r] + EPSV);
        int ot = r >> 4, r16 = r & 15, ch = k >> 6, ks = (k >> 5) & 1, g = (k >> 3) & 3, e = k & 7;
        int lane = g * 16 + r16;
        w2f[((((ot * 12 + ch) * 2 + ks) * 64 + lane) << 3) + e] = f2b(w2[i] * s);
    }
    for (int i = gid; i < HID; i += stp) {
        float s1 = g1[i] * rsqrtf(v1[i] + EPSV);
        be1o[i] = b1[i] - m1[i] * s1;
        float s2 = g2[i] * rsqrtf(v2[i] + EPSV);
        be2o[i] = b2[i] - m2[i] * s2;
    }
    for (int i = gid; i < HID * 9; i += stp) {          // tap-major [q][c], BN2 scale folded
        int q = i / HID, c = i - q * HID;
        float s2 = g2[c] * rsqrtf(v2[c] + EPSV);
        wdsf[i] = wdw[c * 9 + q] * s2;
    }
    for (int i = gid; i < OUP; i += stp) {
        float s3 = g3[i] * rsqrtf(v3[i] + EPSV);
        be3o[i] = b3[i] - m3[i] * s3;
    }
    for (int i = gid; i < BATCH * HWSZ; i += stp) {     // mf + 3x3 dilated md
        int b = i / HWSZ, p = i - b * HWSZ;
        int y = p / WW, xx = p - y * WW;
        float mf = (float)mask[i];
        float md = 0.f;
        for (int dy = -1; dy <= 1; ++dy)
            for (int dx = -1; dx <= 1; ++dx) {
                int yy = y + dy, xc = xx + dx;
                if (yy >= 0 && yy < HH && xc >= 0 && xc < WW)
                    md = fmaxf(md, (float)mask[b * HWSZ + yy * WW + xc]);
            }
        mff[i] = mf;
        mdf[i] = md;
    }
    // h1 guard rows (0 and 57) — full 64 dw
    for (int i = gid; i < BATCH * 384 * 2 * H1ROW; i += stp) {
        int rr = i >> 6, d = i & 63;
        int bcp = rr >> 1, side = rr & 1;
        h1p[((size_t)bcp * H1RPC + (side ? 57 : 0)) * H1ROW + d] = 0;
    }
    // h1 col pads of data rows: dwords 0..3 and 60..63
    for (int i = gid; i < BATCH * 384 * 56 * 8; i += stp) {
        int rr = i >> 3, d = i & 7;
        h1p[((size_t)(rr / 56) * H1RPC + 1 + (rr % 56)) * H1ROW + (d < 4 ? d : 56 + d)] = 0;
    }
}

// ---------------- K1: expand GEMM -> h1 (bf16 pairs, padded rows) ----------------
__launch_bounds__(512, 4)
__global__ void k1_expand(const float* __restrict__ x,
                          const unsigned short* __restrict__ w1f,
                          const float* __restrict__ be1g,
                          const float* __restrict__ mdf,
                          unsigned* __restrict__ h1p)
{
    __shared__ unsigned short xs[128 * XSTR];   // 33.3 KB bf16 x-tile [px][c], odd dw stride
    const int t = threadIdx.x, lane = t & 63, wv = t >> 6;
    const int g = lane >> 4, r16 = lane & 15;
    const int pid = blockIdx.x;
    const int l = (pid & 7) * 150 + (pid >> 3);
    const int hb = l % 3;
    const int pb = (l / 3) % 25;
    const int b  = l / 75;
    const int p0 = pb * 128;
    const int whid = wv & 3;
    const int wpx  = wv >> 2;

    for (int rep = 0; rep < 8; ++rep) {
        int id = t + rep * 512;
        int px = id & 127, c4 = id >> 7;
        int p = p0 + px;
        ushort4 u; u.x = 0; u.y = 0; u.z = 0; u.w = 0;
        if (p < HWSZ) {
            const float* xp = x + ((size_t)(b * INP + c4 * 4)) * HWSZ + p;
            unsigned lo = pkbf(xp[0], xp[HWSZ]);
            unsigned hi = pkbf(xp[2 * HWSZ], xp[3 * HWSZ]);
            u.x = (unsigned short)lo; u.y = (unsigned short)(lo >> 16);
            u.z = (unsigned short)hi; u.w = (unsigned short)(hi >> 16);
        }
        *(ushort4*)&xs[px * XSTR + (((c4 >> 1) ^ (px & 15)) << 3) + ((c4 & 1) << 2)] = u;
    }
    __syncthreads();

    f32x4 acc[4][4];
    #pragma unroll
    for (int mt = 0; mt < 4; ++mt)
        #pragma unroll
        for (int nt = 0; nt < 4; ++nt) {
            acc[mt][nt][0] = 0.f; acc[mt][nt][1] = 0.f;
            acc[mt][nt][2] = 0.f; acc[mt][nt][3] = 0.f;
        }
    const int hbase = hb * 256 + whid * 64;
    const int htb = hbase >> 4;

    #pragma unroll
    for (int ks = 0; ks < 4; ++ks) {
        bf16x8 af[4];
        #pragma unroll
        for (int mt = 0; mt < 4; ++mt)
            af[mt] = *(const bf16x8*)&w1f[((((htb + mt) * 4 + ks) * 64) + lane) << 3];
        #pragma unroll
        for (int nt = 0; nt < 4; ++nt) {
            int px = wpx * 64 + nt * 16 + r16;
            bf16x8 bf = *(const bf16x8*)&xs[px * XSTR + (((ks * 4 + g) ^ r16) << 3)];
            #pragma unroll
            for (int mt = 0; mt < 4; ++mt)
                acc[mt][nt] = __builtin_amdgcn_mfma_f32_16x16x32_bf16(af[mt], bf, acc[mt][nt], 0, 0, 0);
        }
    }

    #pragma unroll
    for (int nt = 0; nt < 4; ++nt) {
        const int pg = p0 + wpx * 64 + nt * 16;
        if (pg >= HWSZ) continue;
        const int p = pg + r16;
        const int row = (p * 9363) >> 19;           // p/56
        const int col = p - row * 56;
        const float md = mdf[b * HWSZ + p];
        #pragma unroll
        for (int mt = 0; mt < 4; ++mt) {
            const float4 be4 = *(const float4*)&be1g[hbase + mt * 16 + g * 4];
            f32x4 a = acc[mt][nt];
            float v0 = fminf(fmaxf(a[0] + be4.x, 0.f), 6.f) * md;
            float v1 = fminf(fmaxf(a[1] + be4.y, 0.f), 6.f) * md;
            float v2 = fminf(fmaxf(a[2] + be4.z, 0.f), 6.f) * md;
            float v3 = fminf(fmaxf(a[3] + be4.w, 0.f), 6.f) * md;
            const int c2 = (hbase >> 1) + mt * 8 + g * 2;
            const size_t ad = ((size_t)(b * 384 + c2) * H1RPC + row + 1) * H1ROW + 4 + col;
            h1p[ad] = pkbf(v0, v1);
            h1p[ad + H1RPC * H1ROW] = pkbf(v2, v3);
        }
    }
}

// ---------------- K23: DMA-staged DW + low-redundancy P ----------------
__launch_bounds__(512, 4)
__global__ void k23(const unsigned* __restrict__ h1p,
                    const unsigned short* __restrict__ w2f,
                    const float* __restrict__ wdsf,
                    const float* __restrict__ be2g,
                    const float* __restrict__ be3g,
                    const float* __restrict__ mff,
                    const float* __restrict__ x,
                    float* __restrict__ out)
{
    __shared__ unsigned stg[32 * CPST];          // 33920 B  h1 [cp 32][4 rows x 64 dw + 9 pad]
    __shared__ unsigned short h2s[112 * H2STR];  // 16128 B  h2 [px][c] swizzled
    __shared__ float mfv_[112];                  //   448 B
    // total 50.5 KB -> 3 blocks/CU capacity

    const int t = threadIdx.x, lane = t & 63, wv = t >> 6;
    const int g = lane >> 4, r16 = lane & 15;
    const int pid = blockIdx.x;
    const int l = (pid & 7) * 56 + (pid >> 3);   // XCD swizzle (448 = 8*56)
    const int strip = l % 28, b = l / 28;
    const int y0 = strip * 2, p0 = strip * 112;

    if (t < 112) mfv_[t] = mff[b * HWSZ + p0 + t];

    // DMA: wave wv stages cp = wv*4 .. wv*4+3; one wave-instr per cp = 4 rows (y0-1..y0+2 -> idx y0..y0+3)
    const unsigned* gb[4];
    unsigned* lb[4];
    #pragma unroll
    for (int i = 0; i < 4; ++i) {
        const int cpw = wv * 4 + i;
        gb[i] = h1p + (((size_t)(b * 384 + cpw) * H1RPC + y0) << 6) + lane * 4;
        lb[i] = &stg[cpw * CPST];
    }
    auto dma = [&](int ch) {
        #pragma unroll
        for (int i = 0; i < 4; ++i)
            __builtin_amdgcn_global_load_lds((GU*)(gb[i] + (size_t)ch * 32 * H1RPC * H1ROW),
                                             (LU*)lb[i], 16, 0, 0);
    };

    // DW mapping: thread -> (cp 32, row2 2, q 8); 2 paired channels x 7 px each
    const int cp_c = t & 31, row2 = (t >> 5) & 1, q = t >> 6;   // q == wave id
    unsigned* const h2d = (unsigned*)h2s;

    auto phaseDW = [&](int ch) {
        f32x2 acc2[7];
        {
            const float2 be2 = *(const float2*)&be2g[ch * 64 + 2 * cp_c];
            #pragma unroll
            for (int j = 0; j < 7; ++j) { acc2[j][0] = be2.x; acc2[j][1] = be2.y; }
        }
        const int w0d = q * 7 + 3;                 // window first dword (col q*7-1)
        #pragma unroll
        for (int dy = 0; dy < 3; ++dy) {
            f32x2 wt0 = *(const f32x2*)&wdsf[(dy * 3 + 0) * HID + ch * 64 + 2 * cp_c];
            f32x2 wt1 = *(const f32x2*)&wdsf[(dy * 3 + 1) * HID + ch * 64 + 2 * cp_c];
            f32x2 wt2 = *(const f32x2*)&wdsf[(dy * 3 + 2) * HID + ch * 64 + 2 * cp_c];
            const unsigned* rb = &stg[cp_c * CPST + (row2 + dy) * H1ROW + w0d];
            f32x2 p[9];
            #pragma unroll
            for (int k = 0; k < 9; ++k) {          // 9 b32, banks = cp*9 + const: clean
                unsigned u = rb[k];
                p[k][0] = blo(u); p[k][1] = bhi(u);
            }
            #pragma unroll
            for (int j = 0; j < 7; ++j) {
                pkfma(acc2[j], p[j], wt0);
                pkfma(acc2[j], p[j + 1], wt1);
                pkfma(acc2[j], p[j + 2], wt2);
            }
        }
        #pragma unroll
        for (int j = 0; j < 7; ++j) {
            const int px = row2 * 56 + q * 7 + j;
            const float mv = mfv_[px];
            float vL = __builtin_amdgcn_fmed3f(acc2[j][0], 0.f, 6.f) * mv;
            float vH = __builtin_amdgcn_fmed3f(acc2[j][1], 0.f, 6.f) * mv;
            h2d[px * 36 + (((cp_c >> 2) ^ (px & 7)) << 2) + (cp_c & 3)] = pkbf(vL, vH);
        }
    };

    // P: wave w<7 owns px tile w, ALL 8 out-ch tiles -> 2 h2s b128 reads/wave/chunk
    f32x4 pacc[8];
    #pragma unroll
    for (int ot = 0; ot < 8; ++ot) {
        pacc[ot][0] = 0.f; pacc[ot][1] = 0.f; pacc[ot][2] = 0.f; pacc[ot][3] = 0.f;
    }
    const int ppx = wv * 16 + r16;               // this wave's pixel (wv<7)

    auto phaseP = [&](int ch) {
        if (wv < 7) {
            #pragma unroll
            for (int ks = 0; ks < 2; ++ks) {
                const bf16x8 hb = *(const bf16x8*)&h2s[ppx * H2STR + (((ks * 4 + g) ^ (ppx & 7)) << 3)];
                #pragma unroll
                for (int ot = 0; ot < 8; ++ot) {
                    const bf16x8 pw = *(const bf16x8*)&w2f[((((ot * 12 + ch) * 2 + ks) * 64) + lane) << 3];
                    pacc[ot] = __builtin_amdgcn_mfma_f32_16x16x32_bf16(pw, hb, pacc[ot], 0, 0, 0);
                }
            }
        }
    };

    // ---- main loop: DMA(ch+1) issued after DW barrier, lands under P ----
    dma(0);
    __syncthreads();                              // DMA landed (vmcnt drained by barrier)
    for (int ch = 0; ch < 12; ++ch) {
        phaseDW(ch);
        __syncthreads();                          // stg reads done; h2s written
        if (ch + 1 < 12) dma(ch + 1);             // overwrite stg while P runs
        phaseP(ch);
        __syncthreads();                          // DMA landed; h2s free
    }

    // ---- epilogue: out = x + (proj + be3) * mf ----
    if (wv < 7) {
        const float mv = mfv_[ppx];
        #pragma unroll
        for (int ot = 0; ot < 8; ++ot) {
            const int ob = ot * 16 + g * 4;
            const float4 be4 = *(const float4*)&be3g[ob];
            const size_t base = (size_t)(b * OUP + ob) * HWSZ + p0 + ppx;
            out[base]            = x[base]            + (pacc[ot][0] + be4.x) * mv;
            out[base + HWSZ]     = x[base + HWSZ]     + (pacc[ot][1] + be4.y) * mv;
            out[base + 2 * HWSZ] = x[base + 2 * HWSZ] + (pacc[ot][2] + be4.z) * mv;
            out[base + 3 * HWSZ] = x[base + 3 * HWSZ] + (pacc[ot][3] + be4.w) * mv;
        }
    }
}

extern "C" void kernel_launch(void* const* d_in, const int* in_sizes, int n_in,
                              void* d_out, int out_size, void* d_ws, size_t ws_size,
                              hipStream_t stream) {
    (void)in_sizes; (void)n_in; (void)out_size; (void)ws_size;
    const float* x   = (const float*)d_in[0];
    const float* w1  = (const float*)d_in[1];
    const float* g1  = (const float*)d_in[2];
    const float* b1  = (const float*)d_in[3];
    const float* m1  = (const float*)d_in[4];
    const float* v1  = (const float*)d_in[5];
    const float* wdw = (const float*)d_in[6];
    const float* g2  = (const float*)d_in[7];
    const float* b2  = (const float*)d_in[8];
    const float* m2  = (const float*)d_in[9];
    const float* v2  = (const float*)d_in[10];
    const float* w2  = (const float*)d_in[11];
    const float* g3  = (const float*)d_in[12];
    const float* b3  = (const float*)d_in[13];
    const float* m3  = (const float*)d_in[14];
    const float* v3  = (const float*)d_in[15];
    const int*  mask = (const int*)d_in[16];
    float* out = (float*)d_out;

    char* ws = (char*)d_ws;
    unsigned short* w1f = (unsigned short*)ws;                 // 196608 B
    unsigned short* w2f = (unsigned short*)(ws + 196608);      // 196608 B
    float* be1o = (float*)(ws + 393216);                       // 3072 B
    float* wdsf = (float*)(ws + 396288);                       // 27648 B  [9][768]
    float* be2o = (float*)(ws + 423936);                       // 3072 B
    float* be3o = (float*)(ws + 427008);                       // 512 B
    float* mdf  = (float*)(ws + 427520);                       // 200704 B
    float* mff  = (float*)(ws + 628224);                       // 200704 B
    unsigned* h1p = (unsigned*)(ws + 828928);                  // 91226112 B ([b][cp384][58][64] dw)

    prep<<<256, 256, 0, stream>>>(w1, g1, b1, m1, v1, wdw, g2, b2, m2, v2,
                                  w2, g3, b3, m3, v3, mask,
                                  w1f, w2f, be1o, wdsf, be2o, be3o, mdf, mff, h1p);
    k1_expand<<<dim3(1200), 512, 0, stream>>>(x, w1f, be1o, mdf, h1p);
    k23<<<dim3(448), 512, 0, stream>>>(h1p, w2f, wdsf, be2o, be3o, mff, x, out);
}